// Round 3
// baseline (591.422 us; speedup 1.0000x reference)
//
#include <hip/hip_runtime.h>
#include <hip/hip_bf16.h>

// LocalGNN forward: out = [x, h1, h2, h3] @ W^T + b, h_{k+1} = Ghat h_k.
// Ghat = D (G+I) D materialized ONCE in bf16, pre-swizzled into MFMA A-frag
// order so prop_gemm's HBM traffic is pure contiguous streams (DRAM-page
// friendly). h pre-swizzled into B-frag order (hF, 2 MB, L2-resident).
// B=4, N=4096, DIM=64. fp32 in/out, bf16 MFMA internally (2% rel tol).

typedef __attribute__((ext_vector_type(4))) float  floatx4;
typedef __attribute__((ext_vector_type(8))) short  short8;

#define NB 4
#define NN 4096
#define ND 64
#define HSZ ((size_t)NB * NN * ND)          // elements of one h buffer
#define HF_B 262144                          // shorts per batch in hF: 128*4*512

__device__ __forceinline__ unsigned short f2bf_bits(float v) {
    __hip_bfloat16 b = __float2bfloat16(v);
    return *reinterpret_cast<unsigned short*>(&b);
}

__device__ __forceinline__ short8 pack8p(const float* v) {
    short8 r;
#pragma unroll
    for (int j = 0; j < 8; ++j) r[j] = (short)f2bf_bits(v[j]);
    return r;
}

// ---------------------------------------------------------------- rowsum -> dinv
__global__ void rowsum_kernel(const float* __restrict__ graph, float* __restrict__ dinv) {
    int row = blockIdx.x;                       // 0 .. NB*NN-1
    const float* g = graph + (size_t)row * NN;
    int t = threadIdx.x;
    float s = 0.f;
#pragma unroll
    for (int q = 0; q < 4; ++q) {
        floatx4 v = *reinterpret_cast<const floatx4*>(g + q * 1024 + t * 4);
        s += v[0] + v[1] + v[2] + v[3];
    }
#pragma unroll
    for (int off = 32; off > 0; off >>= 1) s += __shfl_down(s, off);
    __shared__ float wsum[4];
    if ((t & 63) == 0) wsum[t >> 6] = s;
    __syncthreads();
    if (t == 0) {
        float tot = wsum[0] + wsum[1] + wsum[2] + wsum[3] + 1.0f;  // +1 self loop
        dinv[row] = 1.0f / (sqrtf(tot) + 1e-7f);
    }
}

// ---------------------------------------------------------------- ghat swizzled
// gsw[(((b*256+mt)*128)+kc)*512 + lane*8 + j] = Ghat[b][mt*16+m][kc*32+q*8+j]
// with lane = q*16+m  (MFMA A-frag order: m=lane&15, k=quad*8+j).
// Block = (b, mt): reads 16 rows x 4096 cols coalesced via LDS, writes 1-KB
// contiguous granule groups per wave.
__global__ __launch_bounds__(256) void make_ghat_sw(const float* __restrict__ g,
                                                    const float* __restrict__ dinv,
                                                    unsigned short* __restrict__ gsw) {
    __shared__ float tile[16][524];             // 524-word stride spreads banks
    int bid = blockIdx.x;                        // 0..1023
    int b = bid >> 8, mt = bid & 255;
    int t = threadIdx.x;
    const float* grow  = g + ((size_t)b * NN + mt * 16) * NN;
    const float* dinvb = dinv + (size_t)b * NN;
    size_t outbase = (((size_t)(b * 256 + mt)) * 128) * 512;

    for (int s0 = 0; s0 < NN; s0 += 512) {
        __syncthreads();
#pragma unroll
        for (int li = 0; li < 8; ++li) {
            int flat = li * 1024 + t * 4;
            int r = flat >> 9, cidx = flat & 511;
            floatx4 v = *reinterpret_cast<const floatx4*>(grow + (size_t)r * NN + s0 + cidx);
            *reinterpret_cast<floatx4*>(&tile[r][cidx]) = v;
        }
        __syncthreads();
#pragma unroll
        for (int gg = 0; gg < 4; ++gg) {
            int gi = gg * 256 + t;               // 0..1023
            int kcl = gi >> 6;                   // 0..15
            int ln  = gi & 63;
            int m = ln & 15, q = ln >> 4;
            int i_row = mt * 16 + m;
            float di = dinvb[i_row];
            int kbase = s0 + kcl * 32 + q * 8;
            floatx4 dj0 = *reinterpret_cast<const floatx4*>(dinvb + kbase);
            floatx4 dj1 = *reinterpret_cast<const floatx4*>(dinvb + kbase + 4);
            float v[8];
#pragma unroll
            for (int j = 0; j < 8; ++j) {
                float xv = tile[m][kcl * 32 + q * 8 + j];
                if (kbase + j == i_row) xv += 1.0f;
                float dj = (j < 4) ? dj0[j] : dj1[j - 4];
                v[j] = xv * di * dj;
            }
            short8 o = pack8p(v);
            size_t kc = (size_t)(s0 >> 5) + kcl;
            *reinterpret_cast<short8*>(gsw + outbase + kc * 512 + ln * 8) = o;
        }
    }
}

// ---------------------------------------------------------------- x -> hF frags
// hF[b*HF_B + ((kc*4 + c)*64 + lane)*8 + j] = h[b][kc*32+q*8+j][c*16+m]
__global__ void castF_kernel(const float* __restrict__ x, unsigned short* __restrict__ hF) {
    __shared__ float tile[64][65];
    int b = blockIdx.y, row0 = blockIdx.x * 64;
    size_t base = ((size_t)b * NN + row0) * ND;
    int t = threadIdx.x;
#pragma unroll
    for (int qi = 0; qi < 16; ++qi) {
        int idx = qi * 256 + t;
        tile[idx >> 6][idx & 63] = x[base + idx];
    }
    __syncthreads();
#pragma unroll
    for (int gg = 0; gg < 2; ++gg) {
        int gi = gg * 256 + t;                   // 0..511
        int kcl = gi >> 8;
        int c   = (gi >> 6) & 3;
        int ln  = gi & 63;
        int m = ln & 15, q = ln >> 4;
        float v[8];
#pragma unroll
        for (int j = 0; j < 8; ++j) v[j] = tile[kcl * 32 + q * 8 + j][c * 16 + m];
        short8 o = pack8p(v);
        size_t kc = (size_t)blockIdx.x * 2 + kcl;
        *reinterpret_cast<short8*>(hF + (size_t)b * HF_B + ((kc * 4 + c) * 64 + ln) * 8) = o;
    }
}

// ---------------------------------------------------------------- propagation GEMM
// P[ks][b][i][n] = sum_{j in quarter} Ghat[b][i][j] * h[b][j][n]
// Barrier-free, LDS-free: A streams 32 KB contiguous per wave from gsw;
// B-frags are contiguous dwordx4 from L2-resident hF.
__global__ __launch_bounds__(256, 4) void prop_gemm(const unsigned short* __restrict__ gsw,
                                                    const unsigned short* __restrict__ hF,
                                                    float* __restrict__ P) {
    int wid  = blockIdx.x * 4 + (threadIdx.x >> 6);   // 0..4095
    int lane = threadIdx.x & 63;
    int b  = wid >> 10;
    int ks = (wid >> 8) & 3;
    int mt = wid & 255;
    int m = lane & 15, q = lane >> 4;

    const unsigned short* Ap = gsw + (((size_t)(b * 256 + mt)) * 128 + ks * 32) * 512 + lane * 8;
    const unsigned short* Bp = hF + (size_t)b * HF_B + (size_t)(ks * 32) * 2048 + lane * 8;

    floatx4 acc0 = {0.f,0.f,0.f,0.f}, acc1 = acc0, acc2 = acc0, acc3 = acc0;

#pragma unroll 2
    for (int kc = 0; kc < 32; ++kc) {
        short8 a  = *reinterpret_cast<const short8*>(Ap);
        short8 b0 = *reinterpret_cast<const short8*>(Bp);
        short8 b1 = *reinterpret_cast<const short8*>(Bp + 512);
        short8 b2 = *reinterpret_cast<const short8*>(Bp + 1024);
        short8 b3 = *reinterpret_cast<const short8*>(Bp + 1536);
        Ap += 512;
        Bp += 2048;
        acc0 = __builtin_amdgcn_mfma_f32_16x16x32_bf16(a, b0, acc0, 0, 0, 0);
        acc1 = __builtin_amdgcn_mfma_f32_16x16x32_bf16(a, b1, acc1, 0, 0, 0);
        acc2 = __builtin_amdgcn_mfma_f32_16x16x32_bf16(a, b2, acc2, 0, 0, 0);
        acc3 = __builtin_amdgcn_mfma_f32_16x16x32_bf16(a, b3, acc3, 0, 0, 0);
    }

    float* pout = P + ((size_t)ks * NB + b) * ((size_t)NN * ND);
    int row0 = mt * 16;
    floatx4* accs[4] = {&acc0, &acc1, &acc2, &acc3};
#pragma unroll
    for (int c = 0; c < 4; ++c)
#pragma unroll
        for (int r = 0; r < 4; ++r) {
            int row = row0 + q * 4 + r;
            pout[(size_t)row * ND + c * 16 + m] = (*accs[c])[r];
        }
}

// ---------------------------------------------------------------- combine partials
// h = P0+P1+P2+P3 ; emit bf16 row-major (final-linear A) + B-frag layout (hF).
__global__ void prep_kernel(const float* __restrict__ P,
                            unsigned short* __restrict__ hrow,
                            unsigned short* __restrict__ hF) {
    __shared__ float tile[64][65];
    int b = blockIdx.y, row0 = blockIdx.x * 64;
    size_t base = ((size_t)b * NN + row0) * ND;
    const size_t SZ = HSZ;
    int t = threadIdx.x;
#pragma unroll
    for (int qi = 0; qi < 16; ++qi) {
        int idx = qi * 256 + t;
        int r = idx >> 6, n = idx & 63;
        size_t off = base + idx;
        float s = P[off] + P[SZ + off] + P[2 * SZ + off] + P[3 * SZ + off];
        hrow[off] = f2bf_bits(s);
        tile[r][n] = s;
    }
    __syncthreads();
#pragma unroll
    for (int gg = 0; gg < 2; ++gg) {
        int gi = gg * 256 + t;
        int kcl = gi >> 8;
        int c   = (gi >> 6) & 3;
        int ln  = gi & 63;
        int m = ln & 15, q = ln >> 4;
        float v[8];
#pragma unroll
        for (int j = 0; j < 8; ++j) v[j] = tile[kcl * 32 + q * 8 + j][c * 16 + m];
        short8 o = pack8p(v);
        size_t kc = (size_t)blockIdx.x * 2 + kcl;
        *reinterpret_cast<short8*>(hF + (size_t)b * HF_B + ((kc * 4 + c) * 64 + ln) * 8) = o;
    }
}

// ---------------------------------------------------------------- final linear
__global__ __launch_bounds__(256) void final_linear(const float* __restrict__ x,
                                                    const unsigned short* __restrict__ h1,
                                                    const unsigned short* __restrict__ h2,
                                                    const unsigned short* __restrict__ h3,
                                                    const float* __restrict__ W,
                                                    const float* __restrict__ bias,
                                                    float* __restrict__ out) {
    int wid  = blockIdx.x * 4 + (threadIdx.x >> 6);   // 0..1023
    int lane = threadIdx.x & 63;
    int b = wid >> 8;
    int row0 = (wid & 255) * 16;
    int m = lane & 15, q = lane >> 4;

    floatx4 acc[4];
#pragma unroll
    for (int c = 0; c < 4; ++c) acc[c] = (floatx4){0.f, 0.f, 0.f, 0.f};

    // p = 0 : x (fp32, pack in-kernel)
    {
        const float* A = x + ((size_t)b * NN + row0 + m) * ND;
#pragma unroll
        for (int ki = 0; ki < 2; ++ki) {
            float av[8];
#pragma unroll
            for (int j = 0; j < 8; ++j) av[j] = A[ki * 32 + q * 8 + j];
            short8 af = pack8p(av);
#pragma unroll
            for (int c = 0; c < 4; ++c) {
                const float* Wr = W + (size_t)(c * 16 + m) * 256 + ki * 32 + q * 8;
                float wv[8];
#pragma unroll
                for (int j = 0; j < 8; ++j) wv[j] = Wr[j];
                short8 bf = pack8p(wv);
                acc[c] = __builtin_amdgcn_mfma_f32_16x16x32_bf16(af, bf, acc[c], 0, 0, 0);
            }
        }
    }
    // p = 1..3 : h bf16 direct
    const unsigned short* hs[3] = {h1, h2, h3};
#pragma unroll
    for (int p = 1; p < 4; ++p) {
        const unsigned short* A = hs[p - 1] + ((size_t)b * NN + row0 + m) * ND;
#pragma unroll
        for (int ki = 0; ki < 2; ++ki) {
            short8 af = *reinterpret_cast<const short8*>(A + ki * 32 + q * 8);
#pragma unroll
            for (int c = 0; c < 4; ++c) {
                const float* Wr = W + (size_t)(c * 16 + m) * 256 + p * 64 + ki * 32 + q * 8;
                float wv[8];
#pragma unroll
                for (int j = 0; j < 8; ++j) wv[j] = Wr[j];
                short8 bf = pack8p(wv);
                acc[c] = __builtin_amdgcn_mfma_f32_16x16x32_bf16(af, bf, acc[c], 0, 0, 0);
            }
        }
    }
#pragma unroll
    for (int c = 0; c < 4; ++c) {
        float bb = bias[c * 16 + m];
#pragma unroll
        for (int r = 0; r < 4; ++r) {
            int row = row0 + q * 4 + r;
            out[((size_t)b * NN + row) * ND + c * 16 + m] = acc[c][r] + bb;
        }
    }
}

// ---------------------------------------------------------------- launch
extern "C" void kernel_launch(void* const* d_in, const int* in_sizes, int n_in,
                              void* d_out, int out_size, void* d_ws, size_t ws_size,
                              hipStream_t stream) {
    const float* x     = (const float*)d_in[0];
    const float* graph = (const float*)d_in[1];
    const float* W     = (const float*)d_in[2];
    const float* bias  = (const float*)d_in[3];
    float* out = (float*)d_out;

    // workspace layout (bytes)
    char* w = (char*)d_ws;
    float*          dinv = (float*)w;                                   //  64 KB
    unsigned short* hF   = (unsigned short*)(w + (1 << 16));            //   2 MB
    unsigned short* gsw  = (unsigned short*)(w + (1 << 16) + (1 << 21));// 134 MB
    char* w2 = w + (1 << 16) + (1 << 21) + ((size_t)NB * NN * NN * 2);
    float*          P    = (float*)w2;                                  //  16 MB
    unsigned short* h1   = (unsigned short*)(w2 + 4 * HSZ * 4);
    unsigned short* h2   = h1 + HSZ;
    unsigned short* h3   = h2 + HSZ;

    rowsum_kernel<<<NB * NN, 256, 0, stream>>>(graph, dinv);
    make_ghat_sw<<<NB * 256, 256, 0, stream>>>(graph, dinv, gsw);
    castF_kernel<<<dim3(NN / 64, NB), 256, 0, stream>>>(x, hF);

    unsigned short* houts[3] = {h1, h2, h3};
    for (int s = 0; s < 3; ++s) {
        prop_gemm<<<1024, 256, 0, stream>>>(gsw, hF, P);
        prep_kernel<<<dim3(NN / 64, NB), 256, 0, stream>>>(P, houts[s], hF);
    }
    final_linear<<<256, 256, 0, stream>>>(x, h1, h2, h3, W, bias, out);
}

// Round 4
// 498.478 us; speedup vs baseline: 1.1865x; 1.1865x over previous
//
#include <hip/hip_runtime.h>
#include <hip/hip_bf16.h>

// LocalGNN forward, 4-kernel fused pipeline.
// h_{p+1} = D (G+I) D h_p  computed as  acc = (G+I)bf16 @ (d_j h_p,j)bf16, h=d_i*acc.
// K0: G fp32 -> rowsum(dinv) + (G+I) bf16 A-frag swizzle + x B-frags + W frags.
// K1/K2: prop pass -> hrow_p (bf16 row-major) + hF_p (d-scaled B-frags).
// K3: prop pass 3 + fused [x,h1,h2,h3] @ W^T + bias epilogue.
// B=4, N=4096, DIM=64. fp32 in/out, bf16 MFMA internally (2% rel tol).

typedef __attribute__((ext_vector_type(4))) float  floatx4;
typedef __attribute__((ext_vector_type(8))) short  short8;

#define NB 4
#define NN 4096
#define ND 64
#define HF_B 262144   // shorts per batch in hF: 128 kc * 4 c * 64 ln * 8

__device__ __forceinline__ unsigned short f2bf_bits(float v) {
    __hip_bfloat16 b = __float2bfloat16(v);
    return *reinterpret_cast<unsigned short*>(&b);
}
__device__ __forceinline__ float bf2f(unsigned short u) {
    unsigned int x = ((unsigned int)u) << 16;
    return *reinterpret_cast<float*>(&x);
}
__device__ __forceinline__ short8 pack8p(const float* v) {
    short8 r;
#pragma unroll
    for (int j = 0; j < 8; ++j) r[j] = (short)f2bf_bits(v[j]);
    return r;
}

// ================================================================ K0
// block = tile tt (b, mt16): 16 rows x 4096 cols of G.
__global__ __launch_bounds__(256) void prep_graph(const float* __restrict__ g,
                                                  const float* __restrict__ x,
                                                  const float* __restrict__ W,
                                                  float* __restrict__ dinv,
                                                  unsigned short* __restrict__ gswz,
                                                  unsigned short* __restrict__ hF0,
                                                  unsigned short* __restrict__ Wf) {
    __shared__ float tile[16][516];
    __shared__ float dl[16];
    int tt = blockIdx.x;                 // 0..1023
    int b = tt >> 8, mt = tt & 255;
    int t = threadIdx.x;
    const float* grow = g + ((size_t)b * NN + mt * 16) * NN;
    size_t outbase = (size_t)tt * 128 * 512;
    float rs = 0.f;

    for (int s0 = 0; s0 < NN; s0 += 512) {
        __syncthreads();
#pragma unroll
        for (int it = 0; it < 8; ++it) {
            int f4 = it * 256 + t;                       // float4 index 0..2047
            int r = f4 >> 7, c4 = f4 & 127;
            floatx4 v = *reinterpret_cast<const floatx4*>(grow + (size_t)r * NN + s0 + c4 * 4);
            *reinterpret_cast<floatx4*>(&tile[r][c4 * 4]) = v;
        }
        __syncthreads();
        // rowsum partial: thread t -> row t>>4, cols (t&15) + 16*j (bank-spread)
        {
            int r = t >> 4, c0 = t & 15;
            float s = 0.f;
#pragma unroll
            for (int j2 = 0; j2 < 32; ++j2) s += tile[r][c0 + j2 * 16];
            rs += s;
        }
        // swizzle+write A-frags: 1024 short8 per chunk -> 4/thread
#pragma unroll
        for (int gg = 0; gg < 4; ++gg) {
            int gi = gg * 256 + t;
            int kcl = gi >> 6;                           // 0..15
            int ln = gi & 63;
            int m = ln & 15, q = ln >> 4;
            int i_row = mt * 16 + m;
            int kbase = s0 + kcl * 32 + q * 8;
            float v[8];
#pragma unroll
            for (int j = 0; j < 8; ++j) {
                float xv = tile[m][kcl * 32 + q * 8 + j];
                if (kbase + j == i_row) xv += 1.0f;      // +I
                v[j] = xv;
            }
            *reinterpret_cast<short8*>(gswz + outbase + ((size_t)((s0 >> 5) + kcl)) * 512 + ln * 8) = pack8p(v);
        }
    }
    // reduce rowsum within 16-lane groups
#pragma unroll
    for (int off = 8; off > 0; off >>= 1) rs += __shfl_down(rs, off, 16);
    if ((t & 15) == 0) {
        int r = t >> 4;
        float d = 1.0f / (sqrtf(rs + 1.0f) + 1e-7f);
        dinv[b * NN + mt * 16 + r] = d;
        dl[r] = d;
    }
    __syncthreads();
    // stage x tile (16x64 floats, contiguous)
    {
        const float* xp = x + ((size_t)b * NN + mt * 16) * ND;
#pragma unroll
        for (int e = 0; e < 4; ++e) {
            int idx = e * 256 + t;
            tile[idx >> 6][idx & 63] = xp[idx];
        }
    }
    __syncthreads();
    // write this tile's half-window of hF0 = d_j * x_j  (kc = mt>>1, parity mt&1)
    if (t < 128) {
        int c = t >> 5, lnl = t & 31;
        int q_loc = lnl >> 4, m = lnl & 15;
        int u = mt & 1;
        int ln = u * 32 + lnl;
        int kc = mt >> 1;
        float v[8];
#pragma unroll
        for (int j = 0; j < 8; ++j) {
            int lr = q_loc * 8 + j;                      // 0..15
            v[j] = dl[lr] * tile[lr][c * 16 + m];
        }
        *reinterpret_cast<short8*>(hF0 + (size_t)b * HF_B + ((size_t)(kc * 4 + c) * 64 + ln) * 8) = pack8p(v);
    }
    // W -> B-frag layout (block 0 only): Wf[kc][c][ln][8] = W[c*16+m][kc*32+q*8+j]
    if (tt == 0) {
#pragma unroll
        for (int e = 0; e < 8; ++e) {
            int wi = e * 256 + t;                        // 0..2047
            int kc = wi >> 8;
            int c = (wi >> 6) & 3;
            int ln = wi & 63;
            int m = ln & 15, q = ln >> 4;
            float v[8];
#pragma unroll
            for (int j = 0; j < 8; ++j) v[j] = W[(size_t)(c * 16 + m) * 256 + kc * 32 + q * 8 + j];
            *reinterpret_cast<short8*>(Wf + ((size_t)(kc * 4 + c) * 64 + ln) * 8) = pack8p(v);
        }
    }
}

// ================================================================ prop core
#define PROP_MAIN()                                                                      \
    int bid = blockIdx.x;                                                                \
    int b = bid >> 7, mk = bid & 127;                                                    \
    int t = threadIdx.x;                                                                 \
    int w = t >> 6, lane = t & 63;                                                       \
    int m = lane & 15, q = lane >> 4;                                                    \
    int tt0 = b * 256 + mk * 2;                                                          \
    const unsigned short* Ap0 = gswz + ((size_t)tt0 * 128 + w * 32) * 512 + lane * 8;    \
    const unsigned short* Ap1 = Ap0 + (size_t)128 * 512;                                 \
    const unsigned short* Bp  = hFin + (size_t)b * HF_B + (size_t)(w * 32) * 2048 + lane * 8; \
    floatx4 acc0[4], acc1[4];                                                            \
    _Pragma("unroll")                                                                    \
    for (int c = 0; c < 4; ++c) { acc0[c] = (floatx4){0.f,0.f,0.f,0.f}; acc1[c] = acc0[c]; } \
    _Pragma("unroll 2")                                                                  \
    for (int kc = 0; kc < 32; ++kc) {                                                    \
        short8 a0 = *reinterpret_cast<const short8*>(Ap0);                               \
        short8 a1 = *reinterpret_cast<const short8*>(Ap1);                               \
        short8 b0 = *reinterpret_cast<const short8*>(Bp);                                \
        short8 b1 = *reinterpret_cast<const short8*>(Bp + 512);                          \
        short8 b2 = *reinterpret_cast<const short8*>(Bp + 1024);                         \
        short8 b3 = *reinterpret_cast<const short8*>(Bp + 1536);                         \
        Ap0 += 512; Ap1 += 512; Bp += 2048;                                              \
        acc0[0] = __builtin_amdgcn_mfma_f32_16x16x32_bf16(a0, b0, acc0[0], 0, 0, 0);     \
        acc1[0] = __builtin_amdgcn_mfma_f32_16x16x32_bf16(a1, b0, acc1[0], 0, 0, 0);     \
        acc0[1] = __builtin_amdgcn_mfma_f32_16x16x32_bf16(a0, b1, acc0[1], 0, 0, 0);     \
        acc1[1] = __builtin_amdgcn_mfma_f32_16x16x32_bf16(a1, b1, acc1[1], 0, 0, 0);     \
        acc0[2] = __builtin_amdgcn_mfma_f32_16x16x32_bf16(a0, b2, acc0[2], 0, 0, 0);     \
        acc1[2] = __builtin_amdgcn_mfma_f32_16x16x32_bf16(a1, b2, acc1[2], 0, 0, 0);     \
        acc0[3] = __builtin_amdgcn_mfma_f32_16x16x32_bf16(a0, b3, acc0[3], 0, 0, 0);     \
        acc1[3] = __builtin_amdgcn_mfma_f32_16x16x32_bf16(a1, b3, acc1[3], 0, 0, 0);     \
    }                                                                                    \
    if (t < 32) dl[t] = dinv[b * NN + mk * 32 + t];                                      \
    for (int u = 0; u < 2; ++u) {                                                        \
        __syncthreads();                                                                 \
        floatx4* acc = u ? acc1 : acc0;                                                  \
        _Pragma("unroll")                                                                \
        for (int c = 0; c < 4; ++c)                                                      \
            _Pragma("unroll")                                                            \
            for (int r = 0; r < 4; ++r) buf[w][q * 4 + r][c * 16 + m] = acc[c][r];       \
        __syncthreads();                                                                 \
        _Pragma("unroll")                                                                \
        for (int e = 0; e < 4; ++e) {                                                    \
            int idx = e * 256 + t;                                                       \
            int r = idx >> 6, col = idx & 63;                                            \
            float s = buf[0][r][col] + buf[1][r][col] + buf[2][r][col] + buf[3][r][col]; \
            int lr = u * 16 + r;                                                         \
            hsh[lr][col] = f2bf_bits(dl[lr] * s);                                        \
        }                                                                                \
    }                                                                                    \
    __syncthreads();

// K1/K2: emit hrow_p + hF_p
__global__ __launch_bounds__(256) void prop_pass(const unsigned short* __restrict__ gswz,
                                                 const unsigned short* __restrict__ hFin,
                                                 const float* __restrict__ dinv,
                                                 unsigned short* __restrict__ hrow,
                                                 unsigned short* __restrict__ hFout) {
    __shared__ float buf[4][16][68];
    __shared__ unsigned short hsh[32][64];
    __shared__ float dl[32];
    PROP_MAIN()
    // hrow: coalesced bf16 store of 32x64
    {
        unsigned short* hp = hrow + ((size_t)b * NN + mk * 32) * ND;
#pragma unroll
        for (int e = 0; e < 8; ++e) {
            int idx = e * 256 + t;
            hp[idx] = hsh[idx >> 6][idx & 63];
        }
    }
    // hF: kc = mk, 256 short8 -> 1/thread, value = d_j * h_j
    {
        int c = t >> 6, ln = t & 63;
        int mm = ln & 15, qq = ln >> 4;
        float v[8];
#pragma unroll
        for (int j = 0; j < 8; ++j) {
            int lr = qq * 8 + j;                         // 0..31
            v[j] = dl[lr] * bf2f(hsh[lr][c * 16 + mm]);
        }
        *reinterpret_cast<short8*>(hFout + (size_t)b * HF_B + ((size_t)(mk * 4 + c) * 64 + ln) * 8) = pack8p(v);
    }
}

// K3: pass 3 + fused final linear: out = [x,h1,h2,h3] @ W^T + bias
__global__ __launch_bounds__(256) void prop_final(const unsigned short* __restrict__ gswz,
                                                  const unsigned short* __restrict__ hFin,
                                                  const float* __restrict__ dinv,
                                                  const float* __restrict__ x,
                                                  const unsigned short* __restrict__ hrow1,
                                                  const unsigned short* __restrict__ hrow2,
                                                  const unsigned short* __restrict__ Wf,
                                                  const float* __restrict__ bias,
                                                  float* __restrict__ out) {
    __shared__ float buf[4][16][68];
    __shared__ unsigned short hsh[32][64];
    __shared__ float dl[32];
    PROP_MAIN()
    // epilogue: waves 0,1 -> tiles u=0,1 (32 MFMA each)
    if (w < 2) {
        int u = w;
        int grow = b * NN + mk * 32 + u * 16 + m;        // A row for this lane
        floatx4 facc[4];
#pragma unroll
        for (int c = 0; c < 4; ++c) facc[c] = (floatx4){0.f, 0.f, 0.f, 0.f};
#pragma unroll
        for (int p = 0; p < 4; ++p) {
#pragma unroll
            for (int ki = 0; ki < 2; ++ki) {
                short8 af;
                if (p == 0) {
                    const float* xp = x + (size_t)grow * ND + ki * 32 + q * 8;
                    float v[8];
#pragma unroll
                    for (int j = 0; j < 8; ++j) v[j] = xp[j];
                    af = pack8p(v);
                } else if (p == 1) {
                    af = *reinterpret_cast<const short8*>(hrow1 + (size_t)grow * ND + ki * 32 + q * 8);
                } else if (p == 2) {
                    af = *reinterpret_cast<const short8*>(hrow2 + (size_t)grow * ND + ki * 32 + q * 8);
                } else {
                    af = *reinterpret_cast<const short8*>(&hsh[u * 16 + m][ki * 32 + q * 8]);
                }
                int kc = p * 2 + ki;
#pragma unroll
                for (int c = 0; c < 4; ++c) {
                    short8 bf = *reinterpret_cast<const short8*>(Wf + ((size_t)(kc * 4 + c) * 64 + lane) * 8);
                    facc[c] = __builtin_amdgcn_mfma_f32_16x16x32_bf16(af, bf, facc[c], 0, 0, 0);
                }
            }
        }
#pragma unroll
        for (int c = 0; c < 4; ++c) {
            float bb = bias[c * 16 + m];
#pragma unroll
            for (int r = 0; r < 4; ++r) {
                int row = b * NN + mk * 32 + u * 16 + q * 4 + r;
                out[(size_t)row * ND + c * 16 + m] = facc[c][r] + bb;
            }
        }
    }
}

// ================================================================ launch
extern "C" void kernel_launch(void* const* d_in, const int* in_sizes, int n_in,
                              void* d_out, int out_size, void* d_ws, size_t ws_size,
                              hipStream_t stream) {
    const float* x     = (const float*)d_in[0];
    const float* graph = (const float*)d_in[1];
    const float* W     = (const float*)d_in[2];
    const float* bias  = (const float*)d_in[3];
    float* out = (float*)d_out;

    // workspace layout (bytes)
    char* w = (char*)d_ws;
    float*          dinv  = (float*)w;                         //  64 KB
    unsigned short* Wf    = (unsigned short*)(w + (1 << 16));  //  16 KB
    unsigned short* hFa   = (unsigned short*)(w + (1 << 17));  //   2 MB
    unsigned short* hFb   = hFa + (size_t)NB * HF_B;           //   2 MB
    unsigned short* hrow1 = hFb + (size_t)NB * HF_B;           //   2 MB
    unsigned short* hrow2 = hrow1 + (size_t)NB * NN * ND;      //   2 MB
    unsigned short* gswz  = hrow2 + (size_t)NB * NN * ND;      // 134 MB

    prep_graph<<<1024, 256, 0, stream>>>(graph, x, W, dinv, gswz, hFa, Wf);
    prop_pass<<<512, 256, 0, stream>>>(gswz, hFa, dinv, hrow1, hFb);
    prop_pass<<<512, 256, 0, stream>>>(gswz, hFb, dinv, hrow2, hFa);
    prop_final<<<512, 256, 0, stream>>>(gswz, hFa, dinv, x, hrow1, hrow2, Wf, bias, out);
}